// Round 3
// baseline (62.068 us; speedup 1.0000x reference)
//
#include <hip/hip_runtime.h>
#include <math.h>
#include <stdint.h>

#define BN 2048   // nodes
#define KF 512    // IN_F
#define OF 512    // OUT_F
#define NH 8      // heads
#define DD 64     // head dim
#define IT 32     // i-tile (k_attn)
#define JT 64     // j-chunk (k_attn)
#define NC (BN / JT)

typedef __attribute__((ext_vector_type(8))) short short8;
typedef __attribute__((ext_vector_type(4))) float f32x4;
typedef unsigned short ushortT;

static __device__ __forceinline__ ushortT f2bf(float f) {
  unsigned u = __float_as_uint(f);
  u += 0x7fffu + ((u >> 16) & 1u);           // RNE
  return (ushortT)(u >> 16);
}
static __device__ __forceinline__ float bf2f(ushortT b) {
  return __uint_as_float(((unsigned)b) << 16);
}

// ---------------- adj -> bitmask bytes
__global__ __launch_bounds__(256) void k_pack(const int* __restrict__ adj,
                                              uint8_t* __restrict__ adjB) {
  const int b = blockIdx.x * 256 + threadIdx.x;
  const int4 v0 = *(const int4*)(adj + (size_t)b * 8);
  const int4 v1 = *(const int4*)(adj + (size_t)b * 8 + 4);
  unsigned m = (v0.x ? 1u : 0u) | (v0.y ? 2u : 0u) | (v0.z ? 4u : 0u) | (v0.w ? 8u : 0u)
             | (v1.x ? 16u : 0u) | (v1.y ? 32u : 0u) | (v1.z ? 64u : 0u) | (v1.w ? 128u : 0u);
  adjB[b] = (uint8_t)m;
}

// ---------------- fp32 -> bf16 hi/lo split for x and W
__global__ __launch_bounds__(256) void k_prep(const float* __restrict__ x,
                                              const float* __restrict__ W,
                                              ushortT* __restrict__ xh, ushortT* __restrict__ xl,
                                              ushortT* __restrict__ wh, ushortT* __restrict__ wl) {
  const size_t NX = (size_t)BN * KF;
  size_t q = (size_t)(blockIdx.x * 256 + threadIdx.x) * 8;
  const float* src;
  ushortT *dh, *dl;
  if (q < NX) { src = x + q; dh = xh + q; dl = xl + q; }
  else { const size_t r = q - NX; src = W + r; dh = wh + r; dl = wl + r; }
  const float4 v0 = *(const float4*)src;
  const float4 v1 = *(const float4*)(src + 4);
  float v[8];
  *(float4*)&v[0] = v0; *(float4*)&v[4] = v1;
  ushortT h[8], l[8];
#pragma unroll
  for (int i = 0; i < 8; ++i) {
    h[i] = f2bf(v[i]);
    l[i] = f2bf(v[i] - bf2f(h[i]));
  }
  *(int4*)dh = *(const int4*)h;
  *(int4*)dl = *(const int4*)l;
}

// ---------------- MFMA split-bf16 GEMM + fused scores/E-tables/transposed bf16 store
__global__ __launch_bounds__(256) void k_gemm(
    const ushortT* __restrict__ xh, const ushortT* __restrict__ xl,
    const ushortT* __restrict__ wh, const ushortT* __restrict__ wl,
    const float* __restrict__ Wb, const float* __restrict__ av,
    ushortT* __restrict__ hbT, float* __restrict__ E12s, float* __restrict__ E12d) {
  __shared__ __align__(16) ushortT sMem[4 * 4096];   // sAh|sAl|sBh|sBl, 32KB
  __shared__ float sredS[2][64], sredD[2][64];
  ushortT* sAh = sMem;
  ushortT* sAl = sMem + 4096;
  ushortT* sBh = sMem + 8192;
  ushortT* sBl = sMem + 12288;

  const int t   = threadIdx.x;
  const int hh  = blockIdx.x;
  const int i0  = blockIdx.y * 64;
  const int l   = t & 63;
  const int wv  = t >> 6;
  const int mt  = wv & 1;
  const int nt  = wv >> 1;
  const int l15 = l & 15;
  const int lq  = l >> 4;

  f32x4 acc[2][2] = {};

  int4 rA[2][2], rB[2][2];   // [hi/lo][rep]
  {
#pragma unroll
    for (int rep = 0; rep < 2; ++rep) {
      const int S = t + rep * 256, row = S >> 3, s = S & 7;
      const size_t ga = (size_t)(i0 + row) * KF + s * 8;
      const size_t gb = (size_t)(hh * 64 + row) * KF + s * 8;
      rA[0][rep] = *(const int4*)(xh + ga);
      rA[1][rep] = *(const int4*)(xl + ga);
      rB[0][rep] = *(const int4*)(wh + gb);
      rB[1][rep] = *(const int4*)(wl + gb);
    }
  }

  for (int k0 = 0; k0 < 8; ++k0) {
    __syncthreads();
#pragma unroll
    for (int rep = 0; rep < 2; ++rep) {
      const int S = t + rep * 256, row = S >> 3, s = S & 7;
      const int off = row * 64 + ((s ^ (row & 7)) * 8);
      *(int4*)&sAh[off] = rA[0][rep];
      *(int4*)&sAl[off] = rA[1][rep];
      *(int4*)&sBh[off] = rB[0][rep];
      *(int4*)&sBl[off] = rB[1][rep];
    }
    __syncthreads();
    if (k0 < 7) {
      const int kb0 = (k0 + 1) * 64;
#pragma unroll
      for (int rep = 0; rep < 2; ++rep) {
        const int S = t + rep * 256, row = S >> 3, s = S & 7;
        const size_t ga = (size_t)(i0 + row) * KF + kb0 + s * 8;
        const size_t gb = (size_t)(hh * 64 + row) * KF + kb0 + s * 8;
        rA[0][rep] = *(const int4*)(xh + ga);
        rA[1][rep] = *(const int4*)(xl + ga);
        rB[0][rep] = *(const int4*)(wh + gb);
        rB[1][rep] = *(const int4*)(wl + gb);
      }
    }
#pragma unroll
    for (int kb = 0; kb < 2; ++kb) {
      const int s = kb * 4 + lq;
      short8 afh[2], afl[2], bfh[2], bfl[2];
#pragma unroll
      for (int aa = 0; aa < 2; ++aa) {
        const int rowA = mt * 32 + aa * 16 + l15;
        const int offA = rowA * 64 + ((s ^ (rowA & 7)) * 8);
        afh[aa] = *(const short8*)&sAh[offA];
        afl[aa] = *(const short8*)&sAl[offA];
        const int rowB = nt * 32 + aa * 16 + l15;
        const int offB = rowB * 64 + ((s ^ (rowB & 7)) * 8);
        bfh[aa] = *(const short8*)&sBh[offB];
        bfl[aa] = *(const short8*)&sBl[offB];
      }
#pragma unroll
      for (int aa = 0; aa < 2; ++aa)
#pragma unroll
        for (int bb = 0; bb < 2; ++bb) {
          acc[aa][bb] = __builtin_amdgcn_mfma_f32_16x16x32_bf16(afh[aa], bfh[bb], acc[aa][bb], 0, 0, 0);
          acc[aa][bb] = __builtin_amdgcn_mfma_f32_16x16x32_bf16(afh[aa], bfl[bb], acc[aa][bb], 0, 0, 0);
          acc[aa][bb] = __builtin_amdgcn_mfma_f32_16x16x32_bf16(afl[aa], bfh[bb], acc[aa][bb], 0, 0, 0);
        }
    }
  }

  // ---- epilogue ----
  __syncthreads();                              // done reading sMem; reuse as ldsT
  ushortT* ldsT = sMem;                         // [64 f][72 stride] ushort

  float asv[2], adv[2], bv[2];
#pragma unroll
  for (int bb = 0; bb < 2; ++bb) {
    const int fl = nt * 32 + bb * 16 + l15;
    bv[bb]  = Wb[hh * 64 + fl];
    asv[bb] = av[fl];
    adv[bb] = av[64 + fl];
  }
  ushortT hb[2][2][4];
  float sS_l[2][4], sD_l[2][4];
#pragma unroll
  for (int aa = 0; aa < 2; ++aa)
#pragma unroll
    for (int p = 0; p < 4; ++p) {
      float vs = 0.f, vd = 0.f;
#pragma unroll
      for (int bb = 0; bb < 2; ++bb) {
        const float hv = acc[aa][bb][p] + bv[bb];
        hb[aa][bb][p] = f2bf(hv);
        vs = fmaf(hv, asv[bb], vs);
        vd = fmaf(hv, adv[bb], vd);
      }
      vs += __shfl_xor(vs, 1); vs += __shfl_xor(vs, 2);
      vs += __shfl_xor(vs, 4); vs += __shfl_xor(vs, 8);
      vd += __shfl_xor(vd, 1); vd += __shfl_xor(vd, 2);
      vd += __shfl_xor(vd, 4); vd += __shfl_xor(vd, 8);
      sS_l[aa][p] = vs; sD_l[aa][p] = vd;
    }
  if (l15 == 0) {
#pragma unroll
    for (int aa = 0; aa < 2; ++aa)
#pragma unroll
      for (int p = 0; p < 4; ++p) {
        const int row = mt * 32 + aa * 16 + lq * 4 + p;
        sredS[nt][row] = sS_l[aa][p];
        sredD[nt][row] = sD_l[aa][p];
      }
  }
#pragma unroll
  for (int aa = 0; aa < 2; ++aa)
#pragma unroll
    for (int bb = 0; bb < 2; ++bb)
#pragma unroll
      for (int p = 0; p < 4; ++p) {
        const int fl  = nt * 32 + bb * 16 + l15;
        const int row = mt * 32 + aa * 16 + lq * 4 + p;
        ldsT[fl * 72 + row] = hb[aa][bb][p];
      }
  __syncthreads();
  if (t < 64) {
    const float s1 = sredS[0][t] + sredS[1][t];
    const float s2 = sredD[0][t] + sredD[1][t];
    const size_t gi = (size_t)hh * BN + i0 + t;
    E12s[gi * 2]     = __expf(s1);
    E12s[gi * 2 + 1] = __expf(0.2f * s1);
    E12d[gi * 2]     = __expf(s2);
    E12d[gi * 2 + 1] = __expf(0.2f * s2);
  }
  {
    const int f = t >> 2, ic = (t & 3) * 16;
    const int4 v0 = *(const int4*)&ldsT[f * 72 + ic];
    const int4 v1 = *(const int4*)&ldsT[f * 72 + ic + 8];
    ushortT* dst = hbT + (size_t)(hh * 64 + f) * BN + i0 + ic;
    *(int4*)dst       = v0;
    *(int4*)(dst + 8) = v1;
  }
}

// ---------------- fused mask/weight/PV(MFMA)/normalize/ELU
__global__ __launch_bounds__(256) void k_attn(
    const ushortT* __restrict__ hbT, const uint8_t* __restrict__ adjB,
    const float* __restrict__ E12s, const float* __restrict__ E12d,
    float* __restrict__ out) {
  __shared__ __align__(16) ushortT hB[2][64 * 64];   // 16 KB
  __shared__ __align__(16) ushortT wA[2][32 * 64];   // 8 KB
  __shared__ __align__(16) float e12d[BN * 2];       // 16 KB
  __shared__ uint8_t abits[32 * 272];                // 8.5 KB
  __shared__ float denl[32];

  const int t    = threadIdx.x;
  const int hh   = blockIdx.x;
  const int i0   = blockIdx.y * IT;
  const int lane = t & 63;
  const int wv   = t >> 6;

  // stage e12d (float2 pairs) + adj bit rows
  {
    const float4* g = (const float4*)(E12d + (size_t)hh * BN * 2);
#pragma unroll
    for (int rep = 0; rep < 4; ++rep)
      ((float4*)e12d)[t + rep * 256] = g[t + rep * 256];
    const int r = t >> 3, p = t & 7;
    const int4* ga = (const int4*)(adjB + (size_t)(i0 + r) * 256 + p * 32);
    const int4 b0 = ga[0], b1 = ga[1];
    *(int4*)(abits + r * 272 + p * 32)      = b0;
    *(int4*)(abits + r * 272 + p * 32 + 16) = b1;
  }

  const int wi = t >> 3;
  const int jg = t & 7;
  const float2 ei = *(const float2*)&E12s[2 * ((size_t)hh * BN + i0 + wi)];
  const float e1i = ei.x, e2i = ei.y;
  float denp = 0.f;

  const int mt   = wv & 1;
  const int nt0  = (wv >> 1) * 2;
  const int l15  = lane & 15;
  const int kq   = lane >> 4;
  const int arow = mt * 16 + l15;
  const int bn0  = nt0 * 16 + l15;
  f32x4 acc0 = {0.f, 0.f, 0.f, 0.f}, acc1 = {0.f, 0.f, 0.f, 0.f};

  // staging addresses (per thread)
  const int S0 = t, S1 = t + 256;
  const size_t gh0 = (size_t)(hh * 64 + (S0 >> 3)) * BN + (S0 & 7) * 8;
  const size_t gh1 = (size_t)(hh * 64 + (S1 >> 3)) * BN + (S1 & 7) * 8;
  const int lo0 = (S0 >> 3) * 64 + (((S0 & 7) ^ ((S0 >> 3) & 7)) * 8);
  const int lo1 = (S1 >> 3) * 64 + (((S1 & 7) ^ ((S1 >> 3) & 7)) * 8);
  const int loW = wi * 64 + ((jg ^ (wi & 7)) * 8);

  int4 hv0 = *(const int4*)(hbT + gh0);
  int4 hv1 = *(const int4*)(hbT + gh1);

  __syncthreads();   // e12d/abits staged

  // compute w for a chunk -> bf16x8 + den contribution
#define COMPUTE_W(cc, wbv)                                                        \
  {                                                                               \
    const uint64_t bits64 = *(const uint64_t*)(abits + wi * 272 + (cc) * 8);      \
    const unsigned bbyte = (unsigned)(bits64 >> (jg * 8)) & 0xffu;                \
    const float* ep = &e12d[((cc) * 64 + jg * 8) * 2];                            \
    float4 e0 = *(const float4*)(ep + 0);                                         \
    float4 e1 = *(const float4*)(ep + 4);                                         \
    float4 e2 = *(const float4*)(ep + 8);                                         \
    float4 e3 = *(const float4*)(ep + 12);                                        \
    float d1[8], d2[8];                                                           \
    d1[0] = e0.x; d2[0] = e0.y; d1[1] = e0.z; d2[1] = e0.w;                       \
    d1[2] = e1.x; d2[2] = e1.y; d1[3] = e1.z; d2[3] = e1.w;                       \
    d1[4] = e2.x; d2[4] = e2.y; d1[5] = e2.z; d2[5] = e2.w;                       \
    d1[6] = e3.x; d2[6] = e3.y; d1[7] = e3.z; d2[7] = e3.w;                       \
    _Pragma("unroll")                                                             \
    for (int e = 0; e < 8; ++e) {                                                 \
      const float p1 = e1i * d1[e];                                               \
      const float p2 = e2i * d2[e];                                               \
      float w = fmaxf(p1, p2);                                                    \
      w = ((bbyte >> e) & 1u) ? w : 0.f;                                          \
      const ushortT wu = f2bf(w);                                                 \
      (wbv)[e] = (short)wu;                                                       \
      denp += bf2f(wu);                                                           \
    }                                                                             \
  }

  // prologue: chunk 0 into buffers 0
  {
    short8 wb;
    COMPUTE_W(0, wb)
    *(int4*)&hB[0][lo0] = hv0;
    *(int4*)&hB[0][lo1] = hv1;
    *(short8*)&wA[0][loW] = wb;
  }
  __syncthreads();

  for (int c = 0; c < NC; ++c) {
    const ushortT* hBc = hB[c & 1];
    const ushortT* wAc = wA[c & 1];
    short8 wb;
    if (c < NC - 1) {
      const size_t joff = (size_t)(c + 1) * JT;
      hv0 = *(const int4*)(hbT + gh0 + joff);
      hv1 = *(const int4*)(hbT + gh1 + joff);
      COMPUTE_W(c + 1, wb)
    }
#pragma unroll
    for (int kb = 0; kb < 2; ++kb) {
      const int ks = kb * 4 + kq;
      const short8 af  = *(const short8*)(wAc + arow * 64 + ((ks ^ (arow & 7)) * 8));
      const short8 bf0 = *(const short8*)(hBc + bn0 * 64 + ((ks ^ (bn0 & 7)) * 8));
      const short8 bf1 = *(const short8*)(hBc + (bn0 + 16) * 64 + ((ks ^ ((bn0 + 16) & 7)) * 8));
      acc0 = __builtin_amdgcn_mfma_f32_16x16x32_bf16(af, bf0, acc0, 0, 0, 0);
      acc1 = __builtin_amdgcn_mfma_f32_16x16x32_bf16(af, bf1, acc1, 0, 0, 0);
    }
    if (c < NC - 1) {
      ushortT* hBn = hB[(c + 1) & 1];
      ushortT* wAn = wA[(c + 1) & 1];
      *(int4*)&hBn[lo0] = hv0;
      *(int4*)&hBn[lo1] = hv1;
      *(short8*)&wAn[loW] = wb;
    }
    __syncthreads();
  }

  // den: reduce over 8 threads sharing an i-row
  {
    float d = denp;
    d += __shfl_xor(d, 1);
    d += __shfl_xor(d, 2);
    d += __shfl_xor(d, 4);
    if ((t & 7) == 0) denl[wi] = d;
  }
  __syncthreads();

#pragma unroll
  for (int q = 0; q < 4; ++q) {
    const int row = mt * 16 + kq * 4 + q;
    const float rd = 1.f / denl[row];
    float v0 = acc0[q] * rd;
    float v1 = acc1[q] * rd;
    v0 = v0 > 0.f ? v0 : expm1f(v0);
    v1 = v1 > 0.f ? v1 : expm1f(v1);
    out[(size_t)(i0 + row) * OF + hh * 64 + nt0 * 16 + l15]        = v0;
    out[(size_t)(i0 + row) * OF + hh * 64 + (nt0 + 1) * 16 + l15]  = v1;
  }
}

extern "C" void kernel_launch(void* const* d_in, const int* in_sizes, int n_in,
                              void* d_out, int out_size, void* d_ws, size_t ws_size,
                              hipStream_t stream) {
  const float* x  = (const float*)d_in[0];
  const int* adj  = (const int*)d_in[1];
  const float* Ww = (const float*)d_in[2];
  const float* Wb = (const float*)d_in[3];
  const float* a  = (const float*)d_in[4];
  float* outp = (float*)d_out;

  uint8_t* p = (uint8_t*)d_ws;
  ushortT* xh   = (ushortT*)(p + 0x000000);
  ushortT* xl   = (ushortT*)(p + 0x200000);
  ushortT* wh   = (ushortT*)(p + 0x400000);
  ushortT* wl   = (ushortT*)(p + 0x480000);
  ushortT* hbT  = (ushortT*)(p + 0x500000);
  float*   E12s = (float*)  (p + 0x700000);
  float*   E12d = (float*)  (p + 0x720000);
  uint8_t* adjB =            p + 0x740000;

  k_prep<<<dim3(640), 256, 0, stream>>>(x, Ww, xh, xl, wh, wl);
  k_pack<<<dim3(BN * BN / 8 / 256), 256, 0, stream>>>(adj, adjB);
  k_gemm<<<dim3(NH, BN / 64), 256, 0, stream>>>(xh, xl, wh, wl, Wb, a, hbT, E12s, E12d);
  k_attn<<<dim3(NH, BN / IT), 256, 0, stream>>>(hbT, adjB, E12s, E12d, outp);
}